// Round 2
// baseline (329.902 us; speedup 1.0000x reference)
//
#include <hip/hip_runtime.h>
#include <stdint.h>

#define NB 4
#define NWS 64
#define TT 65536
#define TCC 1024
#define CEE 128
#define WW 16

#define INV2PI 0.15915494309189535f

// ws layout (float offsets)
#define OFF_FILM 0
#define OFF_W0S  (OFF_FILM + NB*256*TCC)          // film: 1048576 floats
#define OFF_B0S  (OFF_W0S + NWS*WW)
#define OFF_W1S  (OFF_B0S + NWS*WW)
#define OFF_B1S  (OFF_W1S + NWS*WW*WW)
#define OFF_W2S  (OFF_B1S + NWS*WW)
#define OFF_B2S  (OFF_W2S + NWS*WW)
#define OFF_MIX  (OFF_B2S + NWS)
#define OFF_PART (OFF_MIX + NWS)                  // 4*NB*TT floats

__device__ __forceinline__ float sinrev(float r) {
  // sin(2*pi*r); weights/biases pre-scaled by 1/2pi
#if __has_builtin(__builtin_amdgcn_fractf) && __has_builtin(__builtin_amdgcn_sinf)
  return __builtin_amdgcn_sinf(__builtin_amdgcn_fractf(r));
#else
  float fr = r - floorf(r);
  return __sinf(fr * 6.283185307179586f);
#endif
}

// ---------------- prep: pre-scale shaper weights into ws -------------------
__global__ __launch_bounds__(256) void k_prep(
    const float* __restrict__ iscale,
    const float* __restrict__ w0, const float* __restrict__ b0,
    const float* __restrict__ w1, const float* __restrict__ b1,
    const float* __restrict__ w2, const float* __restrict__ b2,
    const float* __restrict__ mixw,
    float* __restrict__ ws) {
  int i = blockIdx.x * 256 + threadIdx.x;
  if (i < NWS * WW) {
    int n = i / WW;
    ws[OFF_W0S + i] = w0[i] * iscale[n] * INV2PI;
    ws[OFF_B0S + i] = b0[i] * INV2PI;
    ws[OFF_B1S + i] = b1[i] * INV2PI;
    ws[OFF_W2S + i] = w2[i] * INV2PI;
  }
  if (i < NWS) {
    ws[OFF_B2S + i] = b2[i] * INV2PI;
    ws[OFF_MIX + i] = mixw[i];
  }
  if (i < NWS * WW * WW) ws[OFF_W1S + i] = w1[i] * INV2PI;
}

// ---------------- kernel 1: TimeDistributedMLP -> film [B,256,TC] fp32 -----
#define COLS 8
__global__ __launch_bounds__(128) void k_mlp(
    const float* __restrict__ ce,
    const float* __restrict__ w0, const float* __restrict__ b0,
    const float* __restrict__ g0, const float* __restrict__ e0,
    const float* __restrict__ w1, const float* __restrict__ b1,
    const float* __restrict__ g1, const float* __restrict__ e1,
    const float* __restrict__ w2, const float* __restrict__ b2,
    const float* __restrict__ g2, const float* __restrict__ e2,
    const float* __restrict__ w3, const float* __restrict__ b3,
    float* __restrict__ film) {
  const int tid = threadIdx.x;
  const int bx = blockIdx.x;
  const int b = bx >> 7;               // 128 column-groups per batch
  const int tc0 = (bx & 127) * COLS;

  __shared__ __align__(16) float xa[CEE * COLS];
  __shared__ __align__(16) float xb[CEE * COLS];
  __shared__ float red[2][2][COLS];
  __shared__ float stat[2][COLS];

  {
    const float* src = ce + ((size_t)(b * CEE + tid)) * TCC + tc0;
    float4 v0 = *(const float4*)(src);
    float4 v1 = *(const float4*)(src + 4);
    float* dst = xa + tid * COLS;
    *(float4*)(dst) = v0;
    *(float4*)(dst + 4) = v1;
  }

  float* xin = xa; float* xout = xb;
  const float* Wp[3] = {w0, w1, w2};
  const float* Bp[3] = {b0, b1, b2};
  const float* Gp[3] = {g0, g1, g2};
  const float* Ep[3] = {e0, e1, e2};

  for (int L = 0; L < 3; ++L) {
    __syncthreads();
    const float* wrow = Wp[L] + (size_t)tid * CEE;
    float acc[COLS];
    float bias = Bp[L][tid];
    #pragma unroll
    for (int col = 0; col < COLS; ++col) acc[col] = bias;
    #pragma unroll 8
    for (int c4 = 0; c4 < CEE; c4 += 4) {
      float4 wv = *(const float4*)(wrow + c4);
      const float4* xv = (const float4*)(xin + c4 * COLS);
      #pragma unroll
      for (int j = 0; j < 4; ++j) {
        float w = j == 0 ? wv.x : (j == 1 ? wv.y : (j == 2 ? wv.z : wv.w));
        float4 xlo = xv[2 * j], xhi = xv[2 * j + 1];
        acc[0] = fmaf(w, xlo.x, acc[0]); acc[1] = fmaf(w, xlo.y, acc[1]);
        acc[2] = fmaf(w, xlo.z, acc[2]); acc[3] = fmaf(w, xlo.w, acc[3]);
        acc[4] = fmaf(w, xhi.x, acc[4]); acc[5] = fmaf(w, xhi.y, acc[5]);
        acc[6] = fmaf(w, xhi.z, acc[6]); acc[7] = fmaf(w, xhi.w, acc[7]);
      }
    }

    // LayerNorm over channels (128) per column
    float s[COLS], q[COLS];
    #pragma unroll
    for (int col = 0; col < COLS; ++col) { s[col] = acc[col]; q[col] = acc[col] * acc[col]; }
    #pragma unroll
    for (int m = 1; m < 64; m <<= 1) {
      #pragma unroll
      for (int col = 0; col < COLS; ++col) {
        s[col] += __shfl_xor(s[col], m, 64);
        q[col] += __shfl_xor(q[col], m, 64);
      }
    }
    int wid = tid >> 6;
    if ((tid & 63) == 0) {
      #pragma unroll
      for (int col = 0; col < COLS; ++col) { red[wid][0][col] = s[col]; red[wid][1][col] = q[col]; }
    }
    __syncthreads();
    if (tid < COLS) {
      float st = red[0][0][tid] + red[1][0][tid];
      float qt = red[0][1][tid] + red[1][1][tid];
      float mu = st * (1.0f / CEE);
      float var = qt * (1.0f / CEE) - mu * mu;
      stat[0][tid] = mu;
      stat[1][tid] = rsqrtf(var + 1e-5f);
    }
    __syncthreads();
    float g = Gp[L][tid], e = Ep[L][tid];
    #pragma unroll
    for (int col = 0; col < COLS; ++col) {
      float v = (acc[col] - stat[0][col]) * stat[1][col] * g + e;
      v = fmaxf(v, 0.01f * v);      // LeakyReLU
      xout[tid * COLS + col] = v;
    }
    float* tmp = xin; xin = xout; xout = tmp;
  }
  __syncthreads();

  // final layer CE -> 256 (each thread does outputs tid and tid+128)
  for (int hh = 0; hh < 2; ++hh) {
    int o = hh * 128 + tid;
    const float* wrow = w3 + (size_t)o * CEE;
    float acc[COLS];
    float bias = b3[o];
    #pragma unroll
    for (int col = 0; col < COLS; ++col) acc[col] = bias;
    #pragma unroll 8
    for (int c4 = 0; c4 < CEE; c4 += 4) {
      float4 wv = *(const float4*)(wrow + c4);
      const float4* xv = (const float4*)(xin + c4 * COLS);
      #pragma unroll
      for (int j = 0; j < 4; ++j) {
        float w = j == 0 ? wv.x : (j == 1 ? wv.y : (j == 2 ? wv.z : wv.w));
        float4 xlo = xv[2 * j], xhi = xv[2 * j + 1];
        acc[0] = fmaf(w, xlo.x, acc[0]); acc[1] = fmaf(w, xlo.y, acc[1]);
        acc[2] = fmaf(w, xlo.z, acc[2]); acc[3] = fmaf(w, xlo.w, acc[3]);
        acc[4] = fmaf(w, xhi.x, acc[4]); acc[5] = fmaf(w, xhi.y, acc[5]);
        acc[6] = fmaf(w, xhi.z, acc[6]); acc[7] = fmaf(w, xhi.w, acc[7]);
      }
    }
    float* dst = film + ((size_t)(b * 256 + o)) * TCC + tc0;
    #pragma unroll
    for (int col = 0; col < COLS; ++col) dst[col] = acc[col];
  }
}

// ---------------- kernel 2: FiLM + waveshaper + partial mix ----------------
// grid: 64 tiles x 4 batches x 4 channel-quarters; block 256 threads, 4 t/thread
__global__ __launch_bounds__(256) void k_shape(
    const float* __restrict__ exciter,
    const float* __restrict__ ws,
    float* __restrict__ part) {
  const int tid = threadIdx.x;
  const int bx = blockIdx.x;
  const int tile = bx & 63;
  const int b = (bx >> 6) & 3;
  const int quarter = bx >> 8;       // 0..3
  const int n0 = quarter * 16;
  const int t0 = tile * 1024;
  const int tcbase = tile * 16 - 1;

  __shared__ __align__(16) float W1s[16 * 256];
  __shared__ float W0s[16 * 16], B0s[16 * 16], B1s[16 * 16], W2s[16 * 16];
  __shared__ float B2s[16], MWs[16];
  __shared__ float FL[4 * 16 * 18];

  for (int i = tid; i < 16 * 256; i += 256) W1s[i] = ws[OFF_W1S + n0 * 256 + i];
  if (tid < 16 * 16) {
    W0s[tid] = ws[OFF_W0S + n0 * 16 + tid];
    B0s[tid] = ws[OFF_B0S + n0 * 16 + tid];
    B1s[tid] = ws[OFF_B1S + n0 * 16 + tid];
    W2s[tid] = ws[OFF_W2S + n0 * 16 + tid];
  }
  if (tid < 16) { B2s[tid] = ws[OFF_B2S + n0 + tid]; MWs[tid] = ws[OFF_MIX + n0 + tid]; }
  for (int i = tid; i < 4 * 16 * 18; i += 256) {
    int p = i / (16 * 18);
    int r = i - p * (16 * 18);
    int n = r / 18;
    int j = r - n * 18;
    int tc = tcbase + j;
    tc = tc < 0 ? 0 : (tc > 1023 ? 1023 : tc);
    FL[i] = ws[OFF_FILM + ((size_t)(b * 256 + p * 64 + n0 + n)) * TCC + tc];
  }
  __syncthreads();

  const int tbase = t0 + tid * 4;
  float frac[4]; int j0[4], j1[4];
  #pragma unroll
  for (int u = 0; u < 4; ++u) {
    float pos = ((float)(tbase + u) + 0.5f) * (1.0f / 64.0f) - 0.5f;
    pos = fminf(fmaxf(pos, 0.0f), 1023.0f);
    float fi = floorf(pos);
    int i0 = (int)fi;
    frac[u] = pos - fi;
    int i1 = i0 + 1; if (i1 > 1023) i1 = 1023;
    j0[u] = i0 - tcbase;
    j1[u] = i1 - tcbase;
  }

  float acc[4] = {0.f, 0.f, 0.f, 0.f};
  const float* excb = exciter + ((size_t)b * NWS) * TT + tbase;

  for (int n = 0; n < 16; ++n) {
    const float* f_gi = FL + (0 * 16 + n) * 18;
    const float* f_bi = FL + (1 * 16 + n) * 18;
    const float* f_gn = FL + (2 * 16 + n) * 18;
    const float* f_bn = FL + (3 * 16 + n) * 18;
    float4 ev = *(const float4*)(excb + (size_t)(n0 + n) * TT);
    float evs[4] = {ev.x, ev.y, ev.z, ev.w};
    float x[4], gn_[4], bn_[4];
    #pragma unroll
    for (int u = 0; u < 4; ++u) {
      float a0 = f_gi[j0[u]], a1 = f_gi[j1[u]];
      float gi = a0 + (a1 - a0) * frac[u];
      float c0 = f_bi[j0[u]], c1 = f_bi[j1[u]];
      float bi = c0 + (c1 - c0) * frac[u];
      float d0 = f_gn[j0[u]], d1 = f_gn[j1[u]];
      gn_[u] = d0 + (d1 - d0) * frac[u];
      float e0_ = f_bn[j0[u]], e1_ = f_bn[j1[u]];
      bn_[u] = e0_ + (e1_ - e0_) * frac[u];
      x[u] = fmaf(gi, evs[u], bi);
    }
    float h0[4][16];
    #pragma unroll
    for (int i = 0; i < 16; ++i) {
      float w = W0s[n * 16 + i], bb = B0s[n * 16 + i];
      #pragma unroll
      for (int u = 0; u < 4; ++u) h0[u][i] = sinrev(fmaf(x[u], w, bb));
    }
    float y[4] = {0.f, 0.f, 0.f, 0.f};
    const float4* w1row = (const float4*)(W1s + n * 256);
    #pragma unroll 4
    for (int o = 0; o < 16; ++o) {
      float4 wr0 = w1row[o * 4 + 0], wr1 = w1row[o * 4 + 1];
      float4 wr2 = w1row[o * 4 + 2], wr3 = w1row[o * 4 + 3];
      float bb = B1s[n * 16 + o], w2v = W2s[n * 16 + o];
      #pragma unroll
      for (int u = 0; u < 4; ++u) {
        float tv = bb;
        tv = fmaf(h0[u][0],  wr0.x, tv); tv = fmaf(h0[u][1],  wr0.y, tv);
        tv = fmaf(h0[u][2],  wr0.z, tv); tv = fmaf(h0[u][3],  wr0.w, tv);
        tv = fmaf(h0[u][4],  wr1.x, tv); tv = fmaf(h0[u][5],  wr1.y, tv);
        tv = fmaf(h0[u][6],  wr1.z, tv); tv = fmaf(h0[u][7],  wr1.w, tv);
        tv = fmaf(h0[u][8],  wr2.x, tv); tv = fmaf(h0[u][9],  wr2.y, tv);
        tv = fmaf(h0[u][10], wr2.z, tv); tv = fmaf(h0[u][11], wr2.w, tv);
        tv = fmaf(h0[u][12], wr3.x, tv); tv = fmaf(h0[u][13], wr3.y, tv);
        tv = fmaf(h0[u][14], wr3.z, tv); tv = fmaf(h0[u][15], wr3.w, tv);
        y[u] = fmaf(sinrev(tv), w2v, y[u]);
      }
    }
    float b2v = B2s[n], mwv = MWs[n];
    #pragma unroll
    for (int u = 0; u < 4; ++u) {
      float yy = sinrev(y[u] + b2v);
      acc[u] = fmaf(mwv, fmaf(gn_[u], yy, bn_[u]), acc[u]);
    }
  }
  float4 res = {acc[0], acc[1], acc[2], acc[3]};
  *(float4*)(part + ((size_t)(quarter * NB + b)) * TT + tbase) = res;
}

// ---------------- kernel 3: combine partials, x4 repeat, mixer bias --------
__global__ __launch_bounds__(256) void k_mix(
    const float* __restrict__ part,
    const float* __restrict__ mixb,
    float* __restrict__ out) {
  int i = blockIdx.x * 256 + threadIdx.x;   // over B*T
  float s = part[i] + part[NB * TT + i] + part[2 * NB * TT + i] + part[3 * NB * TT + i]
            + mixb[0];
  float4 v = {s, s, s, s};
  *(float4*)(out + 4 * (size_t)i) = v;
}

extern "C" void kernel_launch(void* const* d_in, const int* in_sizes, int n_in,
                              void* d_out, int out_size, void* d_ws, size_t ws_size,
                              hipStream_t stream) {
  const float* exciter = (const float*)d_in[0];
  const float* ce      = (const float*)d_in[1];
  const float* w0  = (const float*)d_in[2];
  const float* b0  = (const float*)d_in[3];
  const float* g0  = (const float*)d_in[4];
  const float* e0  = (const float*)d_in[5];
  const float* w1  = (const float*)d_in[6];
  const float* b1  = (const float*)d_in[7];
  const float* g1  = (const float*)d_in[8];
  const float* e1  = (const float*)d_in[9];
  const float* w2  = (const float*)d_in[10];
  const float* b2  = (const float*)d_in[11];
  const float* g2  = (const float*)d_in[12];
  const float* e2  = (const float*)d_in[13];
  const float* w3  = (const float*)d_in[14];
  const float* b3  = (const float*)d_in[15];
  const float* iscale = (const float*)d_in[16];
  const float* sw0 = (const float*)d_in[17];
  const float* sb0 = (const float*)d_in[18];
  const float* sw1 = (const float*)d_in[19];
  const float* sb1 = (const float*)d_in[20];
  const float* sw2 = (const float*)d_in[21];
  const float* sb2 = (const float*)d_in[22];
  const float* mixw = (const float*)d_in[23];
  const float* mixb = (const float*)d_in[24];

  float* ws = (float*)d_ws;

  hipLaunchKernelGGL(k_prep, dim3(64), dim3(256), 0, stream,
                     iscale, sw0, sb0, sw1, sb1, sw2, sb2, mixw, ws);
  hipLaunchKernelGGL(k_mlp, dim3(512), dim3(128), 0, stream,
                     ce, w0, b0, g0, e0, w1, b1, g1, e1, w2, b2, g2, e2, w3, b3,
                     ws + OFF_FILM);
  hipLaunchKernelGGL(k_shape, dim3(1024), dim3(256), 0, stream,
                     exciter, ws, ws + OFF_PART);
  hipLaunchKernelGGL(k_mix, dim3(1024), dim3(256), 0, stream,
                     ws + OFF_PART, mixb, (float*)d_out);
}

// Round 3
// 272.660 us; speedup vs baseline: 1.2099x; 1.2099x over previous
//
#include <hip/hip_runtime.h>
#include <stdint.h>

#define NB 4
#define NWS 64
#define TT 65536
#define TCC 1024
#define CEE 128
#define WW 16

#define INV2PI 0.15915494309189535f

// ws layout (float offsets)
#define OFF_FILM  0
#define OFF_W0S   (OFF_FILM + NB*256*TCC)     // 1048576
#define OFF_B0S   (OFF_W0S + 1024)
#define OFF_B1S   (OFF_B0S + 1024)
#define OFF_W2S   (OFF_B1S + 1024)
#define OFF_B2S   (OFF_W2S + 1024)
#define OFF_MIX   (OFF_B2S + 64)
#define OFF_AFRAG (OFF_MIX + 64)              // 16384 f16 = 8192 floats, even offset

typedef _Float16 half4_t __attribute__((ext_vector_type(4)));
typedef float f32x4_t __attribute__((ext_vector_type(4)));

__device__ __forceinline__ float sinrev(float r) {
  // sin(2*pi*r); weights/biases pre-scaled by 1/2pi
#if __has_builtin(__builtin_amdgcn_fractf) && __has_builtin(__builtin_amdgcn_sinf)
  return __builtin_amdgcn_sinf(__builtin_amdgcn_fractf(r));
#else
  float fr = r - floorf(r);
  return __sinf(fr * 6.283185307179586f);
#endif
}

// ---------------- prep: pre-scale shaper weights; pack W1 into A-frags -----
__global__ __launch_bounds__(256) void k_prep(
    const float* __restrict__ iscale,
    const float* __restrict__ w0, const float* __restrict__ b0,
    const float* __restrict__ w1, const float* __restrict__ b1,
    const float* __restrict__ w2, const float* __restrict__ b2,
    const float* __restrict__ mixw,
    float* __restrict__ ws) {
  int i = blockIdx.x * 256 + threadIdx.x;
  if (i < NWS * WW) {
    int n = i / WW;
    ws[OFF_W0S + i] = w0[i] * iscale[n] * INV2PI;
    ws[OFF_B0S + i] = b0[i] * INV2PI;
    ws[OFF_B1S + i] = b1[i] * INV2PI;
    ws[OFF_W2S + i] = w2[i] * INV2PI;
  }
  if (i < NWS) {
    ws[OFF_B2S + i] = b2[i] * INV2PI;
    ws[OFF_MIX + i] = mixw[i];
  }
  if (i < NWS * 64) {
    // A-fragment for v_mfma_f32_16x16x16_f16: lane l holds A[m][k],
    // m = l&15, k = (l>>4)*4 + j   (A = W1[n][m][k] / 2pi, f16)
    int n = i >> 6, l = i & 63;
    int m = l & 15, k0 = (l >> 4) * 4;
    union { uint2 u; half4_t h; } cv;
    #pragma unroll
    for (int j = 0; j < 4; ++j)
      cv.h[j] = (_Float16)(w1[(n * 16 + m) * 16 + k0 + j] * INV2PI);
    ((uint2*)(ws + OFF_AFRAG))[i] = cv.u;
  }
}

// ---------------- kernel 1: TimeDistributedMLP -> film [B,256,TC] fp32 -----
#define COLS 4
__global__ __launch_bounds__(128) void k_mlp(
    const float* __restrict__ ce,
    const float* __restrict__ w0, const float* __restrict__ b0,
    const float* __restrict__ g0, const float* __restrict__ e0,
    const float* __restrict__ w1, const float* __restrict__ b1,
    const float* __restrict__ g1, const float* __restrict__ e1,
    const float* __restrict__ w2, const float* __restrict__ b2,
    const float* __restrict__ g2, const float* __restrict__ e2,
    const float* __restrict__ w3, const float* __restrict__ b3,
    float* __restrict__ film) {
  const int tid = threadIdx.x;
  const int bx = blockIdx.x;
  const int b = bx >> 8;               // 256 column-groups per batch
  const int tc0 = (bx & 255) * COLS;

  __shared__ __align__(16) float xa[CEE * COLS];
  __shared__ __align__(16) float xb[CEE * COLS];
  __shared__ float red[2][2][COLS];
  __shared__ float stat[2][COLS];

  {
    const float* src = ce + ((size_t)(b * CEE + tid)) * TCC + tc0;
    *(float4*)(xa + tid * COLS) = *(const float4*)src;
  }

  float* xin = xa; float* xout = xb;
  const float* Wp[3] = {w0, w1, w2};
  const float* Bp[3] = {b0, b1, b2};
  const float* Gp[3] = {g0, g1, g2};
  const float* Ep[3] = {e0, e1, e2};

  for (int L = 0; L < 3; ++L) {
    __syncthreads();
    const float* wrow = Wp[L] + (size_t)tid * CEE;
    float acc[COLS];
    float bias = Bp[L][tid];
    #pragma unroll
    for (int col = 0; col < COLS; ++col) acc[col] = bias;
    #pragma unroll 8
    for (int c4 = 0; c4 < CEE; c4 += 4) {
      float4 wv = *(const float4*)(wrow + c4);
      #pragma unroll
      for (int j = 0; j < 4; ++j) {
        float w = j == 0 ? wv.x : (j == 1 ? wv.y : (j == 2 ? wv.z : wv.w));
        float4 xv = *(const float4*)(xin + (c4 + j) * COLS);
        acc[0] = fmaf(w, xv.x, acc[0]); acc[1] = fmaf(w, xv.y, acc[1]);
        acc[2] = fmaf(w, xv.z, acc[2]); acc[3] = fmaf(w, xv.w, acc[3]);
      }
    }

    float s[COLS], q[COLS];
    #pragma unroll
    for (int col = 0; col < COLS; ++col) { s[col] = acc[col]; q[col] = acc[col] * acc[col]; }
    #pragma unroll
    for (int m = 1; m < 64; m <<= 1) {
      #pragma unroll
      for (int col = 0; col < COLS; ++col) {
        s[col] += __shfl_xor(s[col], m, 64);
        q[col] += __shfl_xor(q[col], m, 64);
      }
    }
    int wid = tid >> 6;
    if ((tid & 63) == 0) {
      #pragma unroll
      for (int col = 0; col < COLS; ++col) { red[wid][0][col] = s[col]; red[wid][1][col] = q[col]; }
    }
    __syncthreads();
    if (tid < COLS) {
      float st = red[0][0][tid] + red[1][0][tid];
      float qt = red[0][1][tid] + red[1][1][tid];
      float mu = st * (1.0f / CEE);
      float var = qt * (1.0f / CEE) - mu * mu;
      stat[0][tid] = mu;
      stat[1][tid] = rsqrtf(var + 1e-5f);
    }
    __syncthreads();
    float g = Gp[L][tid], e = Ep[L][tid];
    #pragma unroll
    for (int col = 0; col < COLS; ++col) {
      float v = (acc[col] - stat[0][col]) * stat[1][col] * g + e;
      v = fmaxf(v, 0.01f * v);      // LeakyReLU
      xout[tid * COLS + col] = v;
    }
    float* tmp = xin; xin = xout; xout = tmp;
  }
  __syncthreads();

  for (int hh = 0; hh < 2; ++hh) {
    int o = hh * 128 + tid;
    const float* wrow = w3 + (size_t)o * CEE;
    float acc[COLS];
    float bias = b3[o];
    #pragma unroll
    for (int col = 0; col < COLS; ++col) acc[col] = bias;
    #pragma unroll 8
    for (int c4 = 0; c4 < CEE; c4 += 4) {
      float4 wv = *(const float4*)(wrow + c4);
      #pragma unroll
      for (int j = 0; j < 4; ++j) {
        float w = j == 0 ? wv.x : (j == 1 ? wv.y : (j == 2 ? wv.z : wv.w));
        float4 xv = *(const float4*)(xin + (c4 + j) * COLS);
        acc[0] = fmaf(w, xv.x, acc[0]); acc[1] = fmaf(w, xv.y, acc[1]);
        acc[2] = fmaf(w, xv.z, acc[2]); acc[3] = fmaf(w, xv.w, acc[3]);
      }
    }
    float* dst = film + ((size_t)(b * 256 + o)) * TCC + tc0;
    #pragma unroll
    for (int col = 0; col < COLS; ++col) dst[col] = acc[col];
  }
}

// ---------------- kernel 2: FiLM + MFMA waveshaper + mix + x4 + store ------
// grid: 256 tiles x 4 batches; block 256 threads (4 waves x 64 t each)
__global__ __launch_bounds__(256) void k_shape(
    const float* __restrict__ exciter,
    const float* __restrict__ ws,
    const float* __restrict__ mixb,
    float* __restrict__ out) {
  const int tid = threadIdx.x;
  const int lane = tid & 63;
  const int wv = tid >> 6;
  const int bx = blockIdx.x;
  const int blk = bx & 255;
  const int b = bx >> 8;
  const int t0_blk = blk * 256;
  const int tcbase = blk * 4 - 1;

  __shared__ float FL[4 * 64 * 6];
  __shared__ __align__(16) float W0s[NWS * 16], B0s[NWS * 16], B1s[NWS * 16], W2s[NWS * 16];
  __shared__ float B2s[NWS], MWs[NWS];

  for (int i = tid; i < 1024; i += 256) {
    W0s[i] = ws[OFF_W0S + i];
    B0s[i] = ws[OFF_B0S + i];
    B1s[i] = ws[OFF_B1S + i];
    W2s[i] = ws[OFF_W2S + i];
  }
  if (tid < 64) { B2s[tid] = ws[OFF_B2S + tid]; MWs[tid] = ws[OFF_MIX + tid]; }
  for (int i = tid; i < 1536; i += 256) {
    int p = i / 384, r = i - p * 384, n = r / 6, j = r - n * 6;
    int tc = tcbase + j; tc = tc < 0 ? 0 : (tc > 1023 ? 1023 : tc);
    FL[i] = ws[OFF_FILM + ((size_t)(b * 256 + p * 64 + n)) * TCC + tc];
  }
  __syncthreads();

  const int t_own = t0_blk + wv * 64 + lane;
  float pos = ((float)t_own + 0.5f) * (1.0f / 64.0f) - 0.5f;
  pos = fminf(fmaxf(pos, 0.0f), 1023.0f);
  float fi = floorf(pos);
  int i0 = (int)fi;
  float frac = pos - fi;
  int i1 = i0 + 1; if (i1 > 1023) i1 = 1023;
  const int j0 = i0 - tcbase, j1 = i1 - tcbase;

  const int quad = lane >> 4;
  const int l16 = lane & 15;

  float acc = 0.0f;
  const float* excp = exciter + ((size_t)b * NWS) * TT + t_own;
  const uint2* afr = (const uint2*)(ws + OFF_AFRAG);

  float ev = excp[0];
  uint2 af = afr[lane];
  for (int n = 0; n < NWS; ++n) {
    float ev_n = 0.f; uint2 af_n = af;
    if (n < NWS - 1) {
      ev_n = excp[(size_t)(n + 1) * TT];
      af_n = afr[(n + 1) * 64 + lane];
    }
    const float* fgi = FL + (0 * 64 + n) * 6;
    const float* fbi = FL + (1 * 64 + n) * 6;
    const float* fgn = FL + (2 * 64 + n) * 6;
    const float* fbn = FL + (3 * 64 + n) * 6;
    float gi0 = fgi[j0], gi = fmaf(fgi[j1] - gi0, frac, gi0);
    float bi0 = fbi[j0], bi = fmaf(fbi[j1] - bi0, frac, bi0);
    float gn0 = fgn[j0], gn = fmaf(fgn[j1] - gn0, frac, gn0);
    float bn0 = fbn[j0], bn = fmaf(fbn[j1] - bn0, frac, bn0);
    float x = fmaf(gi, ev, bi);

    f32x4_t w0f = *(const f32x4_t*)(W0s + n * 16 + quad * 4);
    f32x4_t b0f = *(const f32x4_t*)(B0s + n * 16 + quad * 4);
    f32x4_t b1f = *(const f32x4_t*)(B1s + n * 16 + quad * 4);
    f32x4_t w2f = *(const f32x4_t*)(W2s + n * 16 + quad * 4);
    half4_t a;
    { union { uint2 u; half4_t h; } cv; cv.u = af; a = cv.h; }
    float b2v = B2s[n], mwv = MWs[n];

    #pragma unroll
    for (int g = 0; g < 4; ++g) {
      float xg = __shfl(x, g * 16 + l16, 64);
      half4_t bfrag;
      #pragma unroll
      for (int k = 0; k < 4; ++k)
        bfrag[k] = (_Float16)sinrev(fmaf(xg, w0f[k], b0f[k]));
      f32x4_t c;
      c[0] = b1f[0]; c[1] = b1f[1]; c[2] = b1f[2]; c[3] = b1f[3];
      f32x4_t d = __builtin_amdgcn_mfma_f32_16x16x16f16(a, bfrag, c, 0, 0, 0);
      float y = 0.0f;
      #pragma unroll
      for (int r = 0; r < 4; ++r) y = fmaf(sinrev(d[r]), w2f[r], y);
      y += __shfl_xor(y, 16, 64);
      y += __shfl_xor(y, 32, 64);
      float z = sinrev(y + b2v);
      float contrib = fmaf(mwv, fmaf(gn, z, bn), acc);
      acc = (quad == g) ? contrib : acc;   // only own-t lanes accumulate
    }
    ev = ev_n; af = af_n;
  }
  float v = acc + mixb[0];
  float4 o4 = {v, v, v, v};
  *(float4*)(out + (size_t)(b * TT + t_own) * 4) = o4;
}

extern "C" void kernel_launch(void* const* d_in, const int* in_sizes, int n_in,
                              void* d_out, int out_size, void* d_ws, size_t ws_size,
                              hipStream_t stream) {
  const float* exciter = (const float*)d_in[0];
  const float* ce      = (const float*)d_in[1];
  const float* w0  = (const float*)d_in[2];
  const float* b0  = (const float*)d_in[3];
  const float* g0  = (const float*)d_in[4];
  const float* e0  = (const float*)d_in[5];
  const float* w1  = (const float*)d_in[6];
  const float* b1  = (const float*)d_in[7];
  const float* g1  = (const float*)d_in[8];
  const float* e1  = (const float*)d_in[9];
  const float* w2  = (const float*)d_in[10];
  const float* b2  = (const float*)d_in[11];
  const float* g2  = (const float*)d_in[12];
  const float* e2  = (const float*)d_in[13];
  const float* w3  = (const float*)d_in[14];
  const float* b3  = (const float*)d_in[15];
  const float* iscale = (const float*)d_in[16];
  const float* sw0 = (const float*)d_in[17];
  const float* sb0 = (const float*)d_in[18];
  const float* sw1 = (const float*)d_in[19];
  const float* sb1 = (const float*)d_in[20];
  const float* sw2 = (const float*)d_in[21];
  const float* sb2 = (const float*)d_in[22];
  const float* mixw = (const float*)d_in[23];
  const float* mixb = (const float*)d_in[24];

  float* ws = (float*)d_ws;

  hipLaunchKernelGGL(k_prep, dim3(16), dim3(256), 0, stream,
                     iscale, sw0, sb0, sw1, sb1, sw2, sb2, mixw, ws);
  hipLaunchKernelGGL(k_mlp, dim3(1024), dim3(128), 0, stream,
                     ce, w0, b0, g0, e0, w1, b1, g1, e1, w2, b2, g2, e2, w3, b3,
                     ws + OFF_FILM);
  hipLaunchKernelGGL(k_shape, dim3(1024), dim3(256), 0, stream,
                     exciter, ws, mixb, (float*)d_out);
}